// Round 9
// baseline (596.953 us; speedup 1.0000x reference)
//
#include <hip/hip_runtime.h>
#include <stdint.h>

typedef unsigned short u16;
typedef unsigned int   u32;

typedef __attribute__((ext_vector_type(8)))  short bf16x8;
typedef __attribute__((ext_vector_type(4)))  float f32x4;
typedef __attribute__((ext_vector_type(16))) float f32x16;

// ---------- bf16 helpers (raw ushort representation) ----------
__device__ __forceinline__ float b2f(u16 u) { return __uint_as_float(((u32)u) << 16); }
__device__ __forceinline__ float blo(u32 u) { return __uint_as_float(u << 16); }
__device__ __forceinline__ float bhi(u32 u) { return __uint_as_float(u & 0xffff0000u); }
__device__ __forceinline__ u16 f2b(float f) {
    u32 x = __float_as_uint(f);
    u32 r = (x + 0x7fffu + ((x >> 16) & 1u)) >> 16;
    return (u16)r;
}

#define NB   4
#define IC   256
#define NPOS 4096
#define CH   64
#define HW   16384

// ======================================================================
// prep: transpose small weights (fp32) + cast QKV weights to bf16
// ======================================================================
__global__ __launch_bounds__(256) void prep_kernel(
    const float* __restrict__ wsw, const float* __restrict__ wcw,
    const float* __restrict__ m1w,
    const float* __restrict__ thw, const float* __restrict__ phw, const float* __restrict__ gw,
    float* __restrict__ wswT, float* __restrict__ wcwT, float* __restrict__ m1wT,
    u16* __restrict__ wbf)
{
    int idx = blockIdx.x * 256 + threadIdx.x;
    if (idx < 65536) {
        wbf[idx]          = f2b(thw[idx]);
        wbf[idx + 65536]  = f2b(phw[idx]);
        wbf[idx + 131072] = f2b(gw[idx]);
    }
    if (idx < 4096) {
        int i = idx >> 6, c = idx & 63;
        wswT[i*64 + c] = wsw[c*64 + i];   // [i][c]: per-i rows contiguous
        wcwT[i*64 + c] = wcw[c*64 + i];
    }
    if (idx < 9216) {
        int o = idx & 15, ct = idx >> 4;
        int t = ct % 9, c = ct / 9;
        m1wT[idx] = m1w[(o*64 + c)*9 + t]; // [(c,t)][o]: 16 contiguous per tap
    }
}

// ======================================================================
// QKV via MFMA. One block: one of {Q,K,V} x [256 o][64 n] tile, K=256.
// ======================================================================
__global__ __launch_bounds__(256) void qkv_mfma_kernel(
    const float* __restrict__ x, const u16* __restrict__ wbf,
    const float* __restrict__ thb, const float* __restrict__ phb, const float* __restrict__ gb,
    u16* __restrict__ Q, u16* __restrict__ K, u16* __restrict__ VT)
{
    __shared__ __align__(16) u32 xT[64*132];     // 33 KB, reused for epilogue transpose
    __shared__ __align__(16) float bias_l[256];
    const int tid  = threadIdx.x;
    const int w    = tid >> 6;
    const int lane = tid & 63;
    const int q4   = lane >> 4;
    const int l    = lane & 15;
    const int n0   = blockIdx.x * 64;
    const int b    = blockIdx.y;
    const int mat  = blockIdx.z;
    const u16* wmat = wbf + mat * 65536;
    const float* bias = (mat == 0) ? thb : (mat == 1) ? phb : gb;

    bias_l[tid] = bias[tid];

    // ---- stage x tile: [n 64][ipair 128] u32 (bf16 pairs), stride 132 ----
    {
        const float* xb = x + ((size_t)b*IC)*NPOS + n0;
        int n   = tid & 63;
        int ip0 = tid >> 6;
        #pragma unroll 4
        for (int p=0; p<32; p++){
            int ip = ip0 + p*4;
            float v0 = xb[(size_t)(2*ip  )*NPOS + n];
            float v1 = xb[(size_t)(2*ip+1)*NPOS + n];
            xT[n*132 + ip] = (u32)f2b(v0) | ((u32)f2b(v1) << 16);
        }
    }
    __syncthreads();

    f32x4 acc[4][4];
    #pragma unroll
    for (int ot=0; ot<4; ot++)
        #pragma unroll
        for (int nt=0; nt<4; nt++) acc[ot][nt] = (f32x4){0.f,0.f,0.f,0.f};

    // ---- K-loop: 8 steps of 32 ----
    #pragma unroll
    for (int f=0; f<8; f++){
        bf16x8 bfrag[4];
        #pragma unroll
        for (int nt=0; nt<4; nt++)
            bfrag[nt] = *(const bf16x8*)&xT[(nt*16 + l)*132 + f*16 + q4*4];
        #pragma unroll
        for (int ot=0; ot<4; ot++){
            bf16x8 afrag = *(const bf16x8*)(wmat + (size_t)(w*64 + ot*16 + l)*256 + f*32 + q4*8);
            #pragma unroll
            for (int nt=0; nt<4; nt++)
                acc[ot][nt] = __builtin_amdgcn_mfma_f32_16x16x32_bf16(afrag, bfrag[nt], acc[ot][nt], 0, 0, 0);
        }
    }
    __syncthreads();   // xT B-frag reads done; reuse buffer for transpose

    if (mat < 2){
        // ---- Q/K: transpose to [n][o] (stride 264 u16), coalesced store ----
        u16* zbuf = (u16*)xT;
        #pragma unroll
        for (int nt=0; nt<4; nt++)
            #pragma unroll
            for (int ot=0; ot<4; ot++){
                int o = w*64 + ot*16 + q4*4;
                float4 bv = *(const float4*)&bias_l[o];
                uint2 pk;
                pk.x = (u32)f2b(acc[ot][nt][0]+bv.x) | ((u32)f2b(acc[ot][nt][1]+bv.y) << 16);
                pk.y = (u32)f2b(acc[ot][nt][2]+bv.z) | ((u32)f2b(acc[ot][nt][3]+bv.w) << 16);
                *(uint2*)&zbuf[(nt*16 + l)*264 + o] = pk;
            }
        __syncthreads();
        u16* dst = ((mat == 0) ? Q : K) + ((size_t)(b*NPOS + n0))*IC;
        int n = tid >> 2, o0 = (tid & 3)*64;
        const u32* src = &xT[n*132 + (tid & 3)*32];
        #pragma unroll
        for (int m=0; m<8; m++)
            *(uint4*)(dst + (size_t)n*IC + o0 + m*8) = ((const uint4*)src)[m];
    } else {
        // ---- V: transpose to [o][n] (stride 66 u16), store VT rows ----
        u16* zbuf = (u16*)xT;
        #pragma unroll
        for (int nt=0; nt<4; nt++)
            #pragma unroll
            for (int ot=0; ot<4; ot++){
                int o = w*64 + ot*16 + q4*4;
                int n = nt*16 + l;
                #pragma unroll
                for (int reg=0; reg<4; reg++)
                    zbuf[(o+reg)*66 + n] = f2b(acc[ot][nt][reg] + bias_l[o+reg]);
            }
        __syncthreads();
        const u32* src = &xT[tid*33];
        u32 tmp[32];
        #pragma unroll
        for (int m=0; m<32; m++) tmp[m] = src[m];
        u16* dst = VT + ((size_t)(b*IC + tid))*NPOS + n0;
        #pragma unroll
        for (int m=0; m<8; m++){
            uint4 v; v.x = tmp[m*4]; v.y = tmp[m*4+1]; v.z = tmp[m*4+2]; v.w = tmp[m*4+3];
            *(uint4*)(dst + m*8) = v;
        }
    }
}

// ======================================================================
// f_c[c][d] = sum_n Q[n][c]*K[n][d]   (per batch), fp32 out
// ======================================================================
__global__ __launch_bounds__(256) void fc_kernel(
    const u16* __restrict__ Q, const u16* __restrict__ K, float* __restrict__ fc)
{
    __shared__ __align__(16) u32 Qt[64*16];
    __shared__ __align__(16) u32 Kt[64*16];
    const int tid = threadIdx.x;
    const int c0 = blockIdx.x * 32, d0 = blockIdx.y * 32, b = blockIdx.z;
    const int tc = tid >> 4, td = tid & 15;
    float a00=0.f,a01=0.f,a10=0.f,a11=0.f;
    for (int nt=0; nt<64; nt++){
        int n0 = nt*64;
        __syncthreads();
        {
            int r = tid >> 2, cu = (tid & 3) * 4;
            *(uint4*)&Qt[r*16+cu] = *(const uint4*)(Q + ((size_t)(b*NPOS + n0 + r))*IC + c0 + cu*2);
            *(uint4*)&Kt[r*16+cu] = *(const uint4*)(K + ((size_t)(b*NPOS + n0 + r))*IC + d0 + cu*2);
        }
        __syncthreads();
        #pragma unroll 8
        for (int nn=0; nn<64; nn++){
            u32 qa = Qt[nn*16 + tc];
            u32 ka = Kt[nn*16 + td];
            float q0 = blo(qa), q1 = bhi(qa);
            float k0 = blo(ka), k1 = bhi(ka);
            a00 = fmaf(q0,k0,a00); a01 = fmaf(q0,k1,a01);
            a10 = fmaf(q1,k0,a10); a11 = fmaf(q1,k1,a11);
        }
    }
    float* fo = fc + (size_t)b*65536 + (size_t)(c0 + tc*2)*256 + d0 + td*2;
    fo[0] = a00; fo[1] = a01; fo[256] = a10; fo[257] = a11;
}

// ======================================================================
// row softmax over f_c (rows of 256)
// ======================================================================
__global__ __launch_bounds__(256) void softmax_fc_kernel(
    const float* __restrict__ fc, float* __restrict__ pc)
{
    __shared__ float red[8];
    const int tid = threadIdx.x;
    const int b = blockIdx.x >> 8, c = blockIdx.x & 255;
    float v = fc[(size_t)b*65536 + (size_t)c*256 + tid];
    float m = v;
    #pragma unroll
    for (int d=32; d>=1; d>>=1) m = fmaxf(m, __shfl_xor(m, d));
    if ((tid & 63) == 0) red[tid>>6] = m;
    __syncthreads();
    m = fmaxf(fmaxf(red[0],red[1]), fmaxf(red[2],red[3]));
    float e = __expf(v - m);
    float s = e;
    #pragma unroll
    for (int d=32; d>=1; d>>=1) s += __shfl_xor(s, d);
    if ((tid & 63) == 0) red[4 + (tid>>6)] = s;
    __syncthreads();
    s = red[4]+red[5]+red[6]+red[7];
    pc[(size_t)b*65536 + (size_t)c*256 + tid] = e / s;
}

// ======================================================================
// y_c[n][d] = sum_o V[n][o]*pc[o][d]  (V from VT[o][n]) -> bf16 chw flat
// ======================================================================
__global__ __launch_bounds__(256) void yc_kernel(
    const u16* __restrict__ VT, const float* __restrict__ pc, u16* __restrict__ ycb)
{
    __shared__ __align__(16) u16 Vt_l[32*64];
    __shared__ __align__(16) float Pt[32*64];
    const int tid = threadIdx.x;
    const int n0 = blockIdx.x * 64, d0 = blockIdx.y * 64, b = blockIdx.z;
    const int tn = tid >> 4, td = tid & 15;
    float acc[4][4];
    #pragma unroll
    for (int j=0;j<4;j++)
        #pragma unroll
        for (int d=0;d<4;d++) acc[j][d]=0.f;
    for (int ot=0; ot<8; ot++){
        int o0 = ot*32;
        __syncthreads();
        {
            int ol = tid >> 3, cc = tid & 7;
            *(uint4*)&Vt_l[ol*64 + cc*8] = *(const uint4*)(VT + ((size_t)(b*IC + o0 + ol))*NPOS + n0 + cc*8);
            const float* ps = pc + (size_t)b*65536 + (size_t)(o0 + ol)*256 + d0 + cc*8;
            *(float4*)&Pt[ol*64 + cc*8]     = *(const float4*)ps;
            *(float4*)&Pt[ol*64 + cc*8 + 4] = *(const float4*)(ps + 4);
        }
        __syncthreads();
        #pragma unroll 4
        for (int kk=0; kk<32; kk++){
            float4 pv = *(const float4*)&Pt[kk*64 + td*4];
            uint2 vp = *(const uint2*)&Vt_l[kk*64 + tn*4];
            float v0 = blo(vp.x), v1 = bhi(vp.x), v2 = blo(vp.y), v3 = bhi(vp.y);
            acc[0][0] = fmaf(v0, pv.x, acc[0][0]); acc[0][1] = fmaf(v0, pv.y, acc[0][1]);
            acc[0][2] = fmaf(v0, pv.z, acc[0][2]); acc[0][3] = fmaf(v0, pv.w, acc[0][3]);
            acc[1][0] = fmaf(v1, pv.x, acc[1][0]); acc[1][1] = fmaf(v1, pv.y, acc[1][1]);
            acc[1][2] = fmaf(v1, pv.z, acc[1][2]); acc[1][3] = fmaf(v1, pv.w, acc[1][3]);
            acc[2][0] = fmaf(v2, pv.x, acc[2][0]); acc[2][1] = fmaf(v2, pv.y, acc[2][1]);
            acc[2][2] = fmaf(v2, pv.z, acc[2][2]); acc[2][3] = fmaf(v2, pv.w, acc[2][3]);
            acc[3][0] = fmaf(v3, pv.x, acc[3][0]); acc[3][1] = fmaf(v3, pv.y, acc[3][1]);
            acc[3][2] = fmaf(v3, pv.z, acc[3][2]); acc[3][3] = fmaf(v3, pv.w, acc[3][3]);
        }
    }
    #pragma unroll
    for (int j=0;j<4;j++){
        u32 lo = (u32)f2b(acc[j][0]) | ((u32)f2b(acc[j][1]) << 16);
        u32 hi = (u32)f2b(acc[j][2]) | ((u32)f2b(acc[j][3]) << 16);
        *(uint2*)&ycb[((size_t)b*NPOS + n0 + tn*4 + j)*IC + d0 + td*4] = make_uint2(lo,hi);
    }
}

// ======================================================================
// MFMA flash attention, split-K, 32x32x16 MFMAs. No-max softmax.
// Bq=64, Bk=64, D=256. LDS exactly 64 KB (2 blocks/CU): P matrix lives
// inside the Kt region after the S-phase barrier. 4 barriers per tile.
// ======================================================================
#define PSTR 72

__global__ __launch_bounds__(256) void flash_mfma_kernel(
    const u16* __restrict__ Q, const u16* __restrict__ K, const u16* __restrict__ VT,
    u16* __restrict__ opart0, u16* __restrict__ opartx, float* __restrict__ lpart,
    int sshift)
{
    __shared__ __align__(16) u32 KVt[16384];      // exactly 64 KB: Kt[0..8191] + Vt[8192..16383]
    u32* Kt = KVt;
    u32* Vt = KVt + 8192;
    u16* Pb = (u16*)KVt;                          // 9216 B inside Kt (valid after S-phase)
    float* lred = (float*)(KVt + 15744);          // 512 B in dead Vt tail (epilogue only)
    const int tid  = threadIdx.x;
    const int w    = tid >> 6;
    const int lane = tid & 63;
    const int l31  = lane & 31;
    const int h    = lane >> 5;
    const int qh   = w & 1;
    const int kh   = w >> 1;     // key-half for S, d-half for PV
    const int S    = 1 << sshift;
    const int b    = blockIdx.y >> sshift;
    const int seg  = blockIdx.y & (S - 1);
    const int n0   = blockIdx.x * 64;
    const int tiles = 64 >> sshift;
    const int kt0   = seg * tiles;

    // Q A-frags (32x32x16 layout: m=l31, k = i*16 + h*8 + j), in registers
    bf16x8 qf[16];
    {
        const u16* qrow = Q + ((size_t)(b*NPOS + n0 + qh*32 + l31))*IC + h*8;
        #pragma unroll
        for (int i=0; i<16; i++)
            qf[i] = *(const bf16x8*)(qrow + i*16);
    }

    f32x16 oacc[4];
    #pragma unroll
    for (int t=0;t<4;t++)
        #pragma unroll
        for (int r=0;r<16;r++) oacc[t][r] = 0.f;
    float lrow[16];
    #pragma unroll
    for (int r=0;r<16;r++) lrow[r] = 0.f;

    for (int kti=0; kti<tiles; kti++){
        const int m0 = (kt0 + kti)*64;
        __syncthreads();   // (1) prior PV reads of Pb/Vt done before restage
        // ---- stage K tile: rows=keys, 256 dims, chunk-swizzled ----
        #pragma unroll
        for (int j=0;j<8;j++){
            int call = w*8 + j;
            int r = call*2 + (lane>>5);
            int c = (lane & 31) ^ (r & 7);
            const u16* g = K + ((size_t)(b*NPOS + m0 + r))*IC + c*8;
            __builtin_amdgcn_global_load_lds(
                (const __attribute__((address_space(1))) u32*)(const void*)g,
                (__attribute__((address_space(3))) u32*)(void*)&Kt[call*256], 16, 0, 0);
        }
        // ---- stage V^T tile: 256 d-rows x 64 keys, chunk-swizzled ----
        #pragma unroll
        for (int j=0;j<8;j++){
            int call = w*8 + j;
            int d = call*8 + (lane>>3);
            int c = (lane & 7) ^ (d & 7);
            const u16* g = VT + ((size_t)(b*IC + d))*NPOS + m0 + c*8;
            __builtin_amdgcn_global_load_lds(
                (const __attribute__((address_space(1))) u32*)(const void*)g,
                (__attribute__((address_space(3))) u32*)(void*)&Vt[call*256], 16, 0, 0);
        }
        __syncthreads();   // (2) staging complete

        // ---- S-tile (32 q x 32 keys), 16 k-steps, 2 interleaved chains ----
        f32x16 se, so;
        #pragma unroll
        for (int r=0;r<16;r++){ se[r]=0.f; so[r]=0.f; }
        const int key = kh*32 + l31;
        #pragma unroll
        for (int i=0; i<16; i+=2){
            int c0 = (i*2 + h) ^ (key & 7);
            bf16x8 kf0 = *(const bf16x8*)((const u16*)Kt + key*256 + c0*8);
            se = __builtin_amdgcn_mfma_f32_32x32x16_bf16(qf[i], kf0, se, 0, 0, 0);
            int c1 = (i*2 + 2 + h) ^ (key & 7);
            bf16x8 kf1 = *(const bf16x8*)((const u16*)Kt + key*256 + c1*8);
            so = __builtin_amdgcn_mfma_f32_32x32x16_bf16(qf[i+1], kf1, so, 0, 0, 0);
        }
        __syncthreads();   // (3) all Kt reads done -> Pb region is free

        // ---- P = exp(S), write to Pb[q][key] ----
        #pragma unroll
        for (int r=0;r<16;r++){
            float p = __expf(se[r] + so[r]);
            lrow[r] += p;
            int qrow = (r&3) + 8*(r>>2) + 4*h;
            Pb[(qh*32 + qrow)*PSTR + key] = f2b(p);
        }
        __syncthreads();   // (4) Pb complete (cross-wave: PV reads both kh halves)

        // ---- O += P V : wave covers 32 q x 128 d (kh half), 4 k-steps ----
        #pragma unroll
        for (int s=0; s<4; s++){
            bf16x8 pa = *(const bf16x8*)(Pb + (qh*32 + l31)*PSTR + s*16 + h*8);
            #pragma unroll
            for (int t=0;t<4;t++){
                int d = kh*128 + t*32 + l31;
                int pos = (s*2 + h) ^ (d & 7);
                bf16x8 vb = *(const bf16x8*)((const u16*)Vt + d*64 + pos*8);
                oacc[t] = __builtin_amdgcn_mfma_f32_32x32x16_bf16(pa, vb, oacc[t], 0, 0, 0);
            }
        }
    }

    __syncthreads();   // all PV reads done; KVt fully reusable for epilogue

    // ---- l: reduce across 32 key-lanes, stash per-kh into lred ----
    #pragma unroll
    for (int r=0;r<16;r++){
        float v = lrow[r];
        v += __shfl_xor(v, 1); v += __shfl_xor(v, 2); v += __shfl_xor(v, 4);
        v += __shfl_xor(v, 8); v += __shfl_xor(v, 16);
        lrow[r] = v;
    }
    if (l31 == 0){
        #pragma unroll
        for (int r=0;r<16;r++){
            int qrow = (r&3) + 8*(r>>2) + 4*h;
            lred[kh*64 + qh*32 + qrow] = lrow[r];
        }
    }

    // ---- transpose unnormalized O via LDS (stride 66 u16) ----
    u16* OT = (u16*)KVt;
    #pragma unroll
    for (int t=0;t<4;t++){
        int d = kh*128 + t*32 + l31;
        #pragma unroll
        for (int r=0;r<16;r++){
            int q = qh*32 + (r&3) + 8*(r>>2) + 4*h;
            OT[d*66 + q] = f2b(oacc[t][r]);
        }
    }
    __syncthreads();
    if (tid < 64)
        lpart[((size_t)(seg*NB + b))*NPOS + n0 + tid] = lred[tid] + lred[64 + tid];
    {
        int d = tid;
        u16* base = (seg == 0) ? opart0 : (opartx + (size_t)(seg-1)*((size_t)NB*IC*NPOS));
        u16* dst = base + (size_t)b*(IC*NPOS) + (size_t)d*NPOS + n0;
        const u32* src = ((const u32*)KVt) + d*33;
        u32 tmp[32];
        #pragma unroll
        for (int m=0; m<32; m++) tmp[m] = src[m];
        #pragma unroll
        for (int m=0; m<8; m++){
            uint4 v; v.x = tmp[m*4]; v.y = tmp[m*4+1]; v.z = tmp[m*4+2]; v.w = tmp[m*4+3];
            *(uint4*)(dst + m*8) = v;
        }
    }
}

// ======================================================================
// combine: ysT = (sum_s O_s) / (sum_s l_s). In-place on opart0 (=ysT).
// ======================================================================
__global__ __launch_bounds__(256) void combine_kernel(
    u16* __restrict__ opart0, const u16* __restrict__ opartx,
    const float* __restrict__ lpart, int S)
{
    const int idx = blockIdx.x * 256 + threadIdx.x;      // 524288 total
    const int b   = idx >> 17;
    const int rem = idx & 131071;
    const int o   = rem >> 9;
    const int n   = (rem & 511) * 8;
    const size_t base = ((size_t)b*IC + o)*NPOS + n;
    float acc[8] = {0,0,0,0,0,0,0,0};
    float L[8]   = {0,0,0,0,0,0,0,0};
    for (int s=0; s<S; s++){
        const u16* p = (s == 0) ? opart0 : (opartx + (size_t)(s-1)*((size_t)NB*IC*NPOS));
        uint4 v = *(const uint4*)(p + base);
        acc[0] += blo(v.x); acc[1] += bhi(v.x);
        acc[2] += blo(v.y); acc[3] += bhi(v.y);
        acc[4] += blo(v.z); acc[5] += bhi(v.z);
        acc[6] += blo(v.w); acc[7] += bhi(v.w);
        const float* lp = lpart + ((size_t)(s*NB + b))*NPOS + n;
        float4 l0 = *(const float4*)lp;
        float4 l1 = *(const float4*)(lp + 4);
        L[0]+=l0.x; L[1]+=l0.y; L[2]+=l0.z; L[3]+=l0.w;
        L[4]+=l1.x; L[5]+=l1.y; L[6]+=l1.z; L[7]+=l1.w;
    }
    uint4 out;
    out.x = (u32)f2b(acc[0]/L[0]) | ((u32)f2b(acc[1]/L[1]) << 16);
    out.y = (u32)f2b(acc[2]/L[2]) | ((u32)f2b(acc[3]/L[3]) << 16);
    out.z = (u32)f2b(acc[4]/L[4]) | ((u32)f2b(acc[5]/L[5]) << 16);
    out.w = (u32)f2b(acc[6]/L[6]) | ((u32)f2b(acc[7]/L[7]) << 16);
    *(uint4*)(opart0 + base) = out;
}

// ======================================================================
// z = x + gs*(Ws@y_s + Ws_b) + gc*(Wc@y_c + Wc_b)   (fp32 out to d_out)
// ======================================================================
__global__ __launch_bounds__(256) void z_kernel(
    const float* __restrict__ x, const u16* __restrict__ ysT, const u16* __restrict__ ycb,
    const float* __restrict__ wswT, const float* __restrict__ wcwT,
    const float* __restrict__ wsb, const float* __restrict__ wcb,
    const float* __restrict__ gs, const float* __restrict__ gc,
    float* __restrict__ zout)
{
    __shared__ __align__(16) float Wsl[64*32];
    __shared__ __align__(16) float Wcl[64*32];
    const int tid = threadIdx.x;
    const int p = blockIdx.x * 256 + tid;
    const int cbase = blockIdx.y * 32;
    const int b = blockIdx.z;
    {
        int i = tid >> 2, c8 = (tid & 3) * 8;
        const float* s1 = wswT + i*64 + cbase + c8;
        const float* s2 = wcwT + i*64 + cbase + c8;
        *(float4*)&Wsl[i*32 + c8]     = *(const float4*)s1;
        *(float4*)&Wsl[i*32 + c8 + 4] = *(const float4*)(s1+4);
        *(float4*)&Wcl[i*32 + c8]     = *(const float4*)s2;
        *(float4*)&Wcl[i*32 + c8 + 4] = *(const float4*)(s2+4);
    }
    __syncthreads();
    float as[32], ac[32];
    #pragma unroll
    for (int c=0;c<32;c++){ as[c]=0.f; ac[c]=0.f; }
    const u16* ysp = ysT + (size_t)b*(IC*NPOS) + p;
    const u16* ycp = ycb + (size_t)b*(IC*NPOS) + p;
    for (int i=0;i<64;i++){
        float ysv = b2f(ysp[(size_t)i*HW]);
        float ycv = b2f(ycp[(size_t)i*HW]);
        #pragma unroll
        for (int c=0;c<32;c++){
            as[c] = fmaf(Wsl[i*32+c], ysv, as[c]);
            ac[c] = fmaf(Wcl[i*32+c], ycv, ac[c]);
        }
    }
    float gsv = gs[0], gcv = gc[0];
    #pragma unroll
    for (int c=0;c<32;c++){
        int cg = cbase + c;
        float xv = x[((size_t)b*CH + cg)*HW + p];
        float zv = fmaf(gsv, as[c] + wsb[cg], xv);
        zv = fmaf(gcv, ac[c] + wcb[cg], zv);
        zout[((size_t)b*CH + cg)*HW + p] = zv;
    }
}

// ======================================================================
// conv3x3 (64->16) + ReLU. 128 px x 2 o-halves per 256-thr block.
// ======================================================================
__global__ __launch_bounds__(256) void conv1_kernel(
    const float* __restrict__ z, const float* __restrict__ m1wT, const float* __restrict__ m1b,
    float* __restrict__ hmid)
{
    const int tid = threadIdx.x;
    const int p = blockIdx.x * 128 + (tid & 127);
    const int oh = (tid >> 7) * 8;
    const int b = blockIdx.y;
    const int y = p >> 7, xx = p & 127;
    float acc[8];
    #pragma unroll
    for (int o=0;o<8;o++) acc[o]=0.f;
    for (int c=0;c<64;c++){
        const float* zp = z + ((size_t)b*CH + c)*HW;
        #pragma unroll
        for (int t=0;t<9;t++){
            int dy = t/3 - 1, dx = t%3 - 1;
            int yy = y + dy, xv = xx + dx;
            float zv = 0.f;
            if (yy >= 0 && yy < 128 && xv >= 0 && xv < 128) zv = zp[yy*128 + xv];
            const float* w = m1wT + (c*9 + t)*16 + oh;
            #pragma unroll
            for (int o=0;o<8;o++) acc[o] = fmaf(w[o], zv, acc[o]);
        }
    }
    #pragma unroll
    for (int o=0;o<8;o++)
        hmid[((size_t)b*16 + oh + o)*HW + p] = fmaxf(acc[o] + m1b[oh + o], 0.f);
}

// ======================================================================
// conv3x3 (16->1), logit out (fp32)
// ======================================================================
__global__ __launch_bounds__(256) void conv2_kernel(
    const float* __restrict__ hmid, const float* __restrict__ m2w, const float* __restrict__ m2b,
    float* __restrict__ logit)
{
    const int idx = blockIdx.x * 256 + threadIdx.x;
    const int b = idx >> 14, p = idx & 16383;
    const int y = p >> 7, xx = p & 127;
    float acc = 0.f;
    for (int c=0;c<16;c++){
        const float* hp = hmid + ((size_t)b*16 + c)*HW;
        #pragma unroll
        for (int t=0;t<9;t++){
            int dy = t/3 - 1, dx = t%3 - 1;
            int yy = y + dy, xv = xx + dx;
            if (yy >= 0 && yy < 128 && xv >= 0 && xv < 128)
                acc = fmaf(m2w[c*9+t], hp[yy*128 + xv], acc);
        }
    }
    logit[idx] = acc + m2b[0];
}

// ======================================================================
extern "C" void kernel_launch(void* const* d_in, const int* in_sizes, int n_in,
                              void* d_out, int out_size, void* d_ws, size_t ws_size,
                              hipStream_t stream)
{
    const float* x    = (const float*)d_in[0];
    const float* g_w  = (const float*)d_in[1];
    const float* g_b  = (const float*)d_in[2];
    const float* th_w = (const float*)d_in[3];
    const float* th_b = (const float*)d_in[4];
    const float* ph_w = (const float*)d_in[5];
    const float* ph_b = (const float*)d_in[6];
    const float* ws_w = (const float*)d_in[7];
    const float* ws_b = (const float*)d_in[8];
    const float* wc_w = (const float*)d_in[9];
    const float* wc_b = (const float*)d_in[10];
    const float* gs   = (const float*)d_in[11];
    const float* gc   = (const float*)d_in[12];
    const float* m1w  = (const float*)d_in[13];
    const float* m1b  = (const float*)d_in[14];
    const float* m2w  = (const float*)d_in[15];
    const float* m2b  = (const float*)d_in[16];

    char* ws = (char*)d_ws;
    u16*   Qb   = (u16*)  (ws + 0);
    u16*   Kb   = (u16*)  (ws + 8388608);
    u16*   VTb  = (u16*)  (ws + 16777216);
    u16*   ysT  = (u16*)  (ws + 25165824);
    u16*   ycb  = (u16*)  (ws + 33554432);
    float* fc   = (float*)(ws + 41943040);
    u16*   wbf  = (u16*)  (ws + 41943040);   // dead before fc_kernel writes fc
    float* pc   = (float*)(ws + 42991616);
    float* hmid = (float*)(ws + 44040192);
    float* lpart= (float*)(ws + 44040192);   // dead hmid region during flash window
    float* wswT = (float*)(ws + 48234496);
    float* wcwT = (float*)(ws + 48250880);
    float* m1wT = (float*)(ws + 48267264);
    u16*   opartx = (u16*)(ws + 48304128);   // (S-1) x 8MB segments

    float* logit = (float*)d_out;
    float* zout  = (float*)d_out + 65536;

    // choose split-K factor by available workspace (constant per session)
    int sshift = 0;
    if (ws_size >= 48304128ULL + 3ULL*8388608ULL)      sshift = 2;
    else if (ws_size >= 48304128ULL + 1ULL*8388608ULL) sshift = 1;

    prep_kernel<<<256, 256, 0, stream>>>(ws_w, wc_w, m1w, th_w, ph_w, g_w,
                                         wswT, wcwT, m1wT, wbf);
    qkv_mfma_kernel<<<dim3(64,4,3), 256, 0, stream>>>(x, wbf, th_b, ph_b, g_b, Qb, Kb, VTb);
    fc_kernel<<<dim3(8,8,4), 256, 0, stream>>>(Qb, Kb, fc);
    softmax_fc_kernel<<<1024, 256, 0, stream>>>(fc, pc);
    yc_kernel<<<dim3(64,4,4), 256, 0, stream>>>(VTb, pc, ycb);
    flash_mfma_kernel<<<dim3(64, NB << sshift), 256, 0, stream>>>(Qb, Kb, VTb, ysT, opartx, lpart, sshift);
    combine_kernel<<<2048, 256, 0, stream>>>(ysT, opartx, lpart, 1 << sshift);
    z_kernel<<<dim3(64,2,4), 256, 0, stream>>>(x, ysT, ycb, wswT, wcwT, ws_b, wc_b, gs, gc, zout);
    conv1_kernel<<<dim3(128,4), 256, 0, stream>>>(zout, m1wT, m1b, hmid);
    conv2_kernel<<<256, 256, 0, stream>>>(hmid, m2w, m2b, logit);
}

// Round 10
// 468.954 us; speedup vs baseline: 1.2729x; 1.2729x over previous
//
#include <hip/hip_runtime.h>
#include <stdint.h>

typedef unsigned short u16;
typedef unsigned int   u32;

typedef __attribute__((ext_vector_type(8)))  short bf16x8;
typedef __attribute__((ext_vector_type(4)))  float f32x4;

// ---------- bf16 helpers (raw ushort representation) ----------
__device__ __forceinline__ float b2f(u16 u) { return __uint_as_float(((u32)u) << 16); }
__device__ __forceinline__ float blo(u32 u) { return __uint_as_float(u << 16); }
__device__ __forceinline__ float bhi(u32 u) { return __uint_as_float(u & 0xffff0000u); }
__device__ __forceinline__ u16 f2b(float f) {
    u32 x = __float_as_uint(f);
    u32 r = (x + 0x7fffu + ((x >> 16) & 1u)) >> 16;
    return (u16)r;
}

#define NB   4
#define IC   256
#define NPOS 4096
#define CH   64
#define HW   16384

// ======================================================================
// prep: transpose small weights (fp32) + cast QKV weights to bf16
// ======================================================================
__global__ __launch_bounds__(256) void prep_kernel(
    const float* __restrict__ wsw, const float* __restrict__ wcw,
    const float* __restrict__ m1w,
    const float* __restrict__ thw, const float* __restrict__ phw, const float* __restrict__ gw,
    float* __restrict__ wswT, float* __restrict__ wcwT, float* __restrict__ m1wT,
    u16* __restrict__ wbf)
{
    int idx = blockIdx.x * 256 + threadIdx.x;
    if (idx < 65536) {
        wbf[idx]          = f2b(thw[idx]);
        wbf[idx + 65536]  = f2b(phw[idx]);
        wbf[idx + 131072] = f2b(gw[idx]);
    }
    if (idx < 4096) {
        int i = idx >> 6, c = idx & 63;
        wswT[i*64 + c] = wsw[c*64 + i];   // [i][c]: per-i rows contiguous
        wcwT[i*64 + c] = wcw[c*64 + i];
    }
    if (idx < 9216) {
        int o = idx & 15, ct = idx >> 4;
        int t = ct % 9, c = ct / 9;
        m1wT[idx] = m1w[(o*64 + c)*9 + t]; // [(c,t)][o]: 16 contiguous per tap
    }
}

// ======================================================================
// QKV via MFMA. One block: one of {Q,K,V} x [256 o][64 n] tile, K=256.
// ======================================================================
__global__ __launch_bounds__(256) void qkv_mfma_kernel(
    const float* __restrict__ x, const u16* __restrict__ wbf,
    const float* __restrict__ thb, const float* __restrict__ phb, const float* __restrict__ gb,
    u16* __restrict__ Q, u16* __restrict__ K, u16* __restrict__ VT)
{
    __shared__ __align__(16) u32 xT[64*132];     // 33 KB, reused for epilogue transpose
    __shared__ __align__(16) float bias_l[256];
    const int tid  = threadIdx.x;
    const int w    = tid >> 6;
    const int lane = tid & 63;
    const int q4   = lane >> 4;
    const int l    = lane & 15;
    const int n0   = blockIdx.x * 64;
    const int b    = blockIdx.y;
    const int mat  = blockIdx.z;
    const u16* wmat = wbf + mat * 65536;
    const float* bias = (mat == 0) ? thb : (mat == 1) ? phb : gb;

    bias_l[tid] = bias[tid];

    // ---- stage x tile: [n 64][ipair 128] u32 (bf16 pairs), stride 132 ----
    {
        const float* xb = x + ((size_t)b*IC)*NPOS + n0;
        int n   = tid & 63;
        int ip0 = tid >> 6;
        #pragma unroll 4
        for (int p=0; p<32; p++){
            int ip = ip0 + p*4;
            float v0 = xb[(size_t)(2*ip  )*NPOS + n];
            float v1 = xb[(size_t)(2*ip+1)*NPOS + n];
            xT[n*132 + ip] = (u32)f2b(v0) | ((u32)f2b(v1) << 16);
        }
    }
    __syncthreads();

    f32x4 acc[4][4];
    #pragma unroll
    for (int ot=0; ot<4; ot++)
        #pragma unroll
        for (int nt=0; nt<4; nt++) acc[ot][nt] = (f32x4){0.f,0.f,0.f,0.f};

    // ---- K-loop: 8 steps of 32 ----
    #pragma unroll
    for (int f=0; f<8; f++){
        bf16x8 bfrag[4];
        #pragma unroll
        for (int nt=0; nt<4; nt++)
            bfrag[nt] = *(const bf16x8*)&xT[(nt*16 + l)*132 + f*16 + q4*4];
        #pragma unroll
        for (int ot=0; ot<4; ot++){
            bf16x8 afrag = *(const bf16x8*)(wmat + (size_t)(w*64 + ot*16 + l)*256 + f*32 + q4*8);
            #pragma unroll
            for (int nt=0; nt<4; nt++)
                acc[ot][nt] = __builtin_amdgcn_mfma_f32_16x16x32_bf16(afrag, bfrag[nt], acc[ot][nt], 0, 0, 0);
        }
    }
    __syncthreads();   // xT B-frag reads done; reuse buffer for transpose

    if (mat < 2){
        // ---- Q/K: transpose to [n][o] (stride 264 u16), coalesced store ----
        u16* zbuf = (u16*)xT;
        #pragma unroll
        for (int nt=0; nt<4; nt++)
            #pragma unroll
            for (int ot=0; ot<4; ot++){
                int o = w*64 + ot*16 + q4*4;
                float4 bv = *(const float4*)&bias_l[o];
                uint2 pk;
                pk.x = (u32)f2b(acc[ot][nt][0]+bv.x) | ((u32)f2b(acc[ot][nt][1]+bv.y) << 16);
                pk.y = (u32)f2b(acc[ot][nt][2]+bv.z) | ((u32)f2b(acc[ot][nt][3]+bv.w) << 16);
                *(uint2*)&zbuf[(nt*16 + l)*264 + o] = pk;
            }
        __syncthreads();
        u16* dst = ((mat == 0) ? Q : K) + ((size_t)(b*NPOS + n0))*IC;
        int n = tid >> 2, o0 = (tid & 3)*64;
        const u32* src = &xT[n*132 + (tid & 3)*32];
        #pragma unroll
        for (int m=0; m<8; m++)
            *(uint4*)(dst + (size_t)n*IC + o0 + m*8) = ((const uint4*)src)[m];
    } else {
        // ---- V: transpose to [o][n] (stride 66 u16), store VT rows ----
        u16* zbuf = (u16*)xT;
        #pragma unroll
        for (int nt=0; nt<4; nt++)
            #pragma unroll
            for (int ot=0; ot<4; ot++){
                int o = w*64 + ot*16 + q4*4;
                int n = nt*16 + l;
                #pragma unroll
                for (int reg=0; reg<4; reg++)
                    zbuf[(o+reg)*66 + n] = f2b(acc[ot][nt][reg] + bias_l[o+reg]);
            }
        __syncthreads();
        const u32* src = &xT[tid*33];
        u32 tmp[32];
        #pragma unroll
        for (int m=0; m<32; m++) tmp[m] = src[m];
        u16* dst = VT + ((size_t)(b*IC + tid))*NPOS + n0;
        #pragma unroll
        for (int m=0; m<8; m++){
            uint4 v; v.x = tmp[m*4]; v.y = tmp[m*4+1]; v.z = tmp[m*4+2]; v.w = tmp[m*4+3];
            *(uint4*)(dst + m*8) = v;
        }
    }
}

// ======================================================================
// fc via MFMA: fc[c][d] = sum_n Q[n][c]*K[n][d]. Split-n partials.
// Block: 64c x 64d x (1024-n range). Grid (4,4,16): z = b*4+nseg.
// ======================================================================
__global__ __launch_bounds__(256) void fc_mfma_kernel(
    const u16* __restrict__ Q, const u16* __restrict__ K, float* __restrict__ fcp)
{
    __shared__ __align__(16) u16 QT[64*72];   // 9 KB each, stride 72 (b128-aligned)
    __shared__ __align__(16) u16 KT[64*72];
    const int tid = threadIdx.x;
    const int w   = tid >> 6;
    const int lane = tid & 63;
    const int q4  = lane >> 4;
    const int l   = lane & 15;
    const int c0  = blockIdx.x * 64;
    const int d0  = blockIdx.y * 64;
    const int b   = blockIdx.z >> 2;
    const int nseg= blockIdx.z & 3;

    f32x4 acc[4];
    #pragma unroll
    for (int dt=0; dt<4; dt++) acc[dt] = (f32x4){0.f,0.f,0.f,0.f};

    for (int chunk=0; chunk<16; chunk++){
        const int n0 = nseg*1024 + chunk*64;
        __syncthreads();
        {   // stage Q/K tiles transposed: [c|d][n], 16 cols per thread
            int r  = tid >> 2;            // n within chunk
            int cq = (tid & 3) * 16;
            const u16* qs = Q + ((size_t)(b*NPOS + n0 + r))*IC + c0 + cq;
            const u16* ks = K + ((size_t)(b*NPOS + n0 + r))*IC + d0 + cq;
            u16 qv[16], kv[16];
            *(uint4*)&qv[0] = *(const uint4*)qs;
            *(uint4*)&qv[8] = *(const uint4*)(qs + 8);
            *(uint4*)&kv[0] = *(const uint4*)ks;
            *(uint4*)&kv[8] = *(const uint4*)(ks + 8);
            #pragma unroll
            for (int j=0;j<16;j++){
                QT[(cq+j)*72 + r] = qv[j];
                KT[(cq+j)*72 + r] = kv[j];
            }
        }
        __syncthreads();
        // D[c][d] += sum_n A[c][n]*B[d][n]; 2 k-steps of 32
        #pragma unroll
        for (int f=0; f<2; f++){
            bf16x8 af = *(const bf16x8*)&QT[(w*16 + l)*72 + f*32 + q4*8];
            #pragma unroll
            for (int dt=0; dt<4; dt++){
                bf16x8 bf2 = *(const bf16x8*)&KT[(dt*16 + l)*72 + f*32 + q4*8];
                acc[dt] = __builtin_amdgcn_mfma_f32_16x16x32_bf16(af, bf2, acc[dt], 0, 0, 0);
            }
        }
    }

    // C layout: col=l (d), row=q4*4+reg (c)
    #pragma unroll
    for (int dt=0; dt<4; dt++)
        #pragma unroll
        for (int reg=0; reg<4; reg++)
            fcp[((size_t)((nseg*NB + b)*256 + c0 + w*16 + q4*4 + reg))*256 + d0 + dt*16 + l] = acc[dt][reg];
}

// ======================================================================
// row softmax over f_c (sums 4 n-partials, rows of 256)
// ======================================================================
__global__ __launch_bounds__(256) void softmax_fc_kernel(
    const float* __restrict__ fcp, float* __restrict__ pc)
{
    __shared__ float red[8];
    const int tid = threadIdx.x;
    const int b = blockIdx.x >> 8, c = blockIdx.x & 255;
    float v = 0.f;
    #pragma unroll
    for (int s=0; s<4; s++)
        v += fcp[((size_t)((s*NB + b)*256 + c))*256 + tid];
    float m = v;
    #pragma unroll
    for (int d=32; d>=1; d>>=1) m = fmaxf(m, __shfl_xor(m, d));
    if ((tid & 63) == 0) red[tid>>6] = m;
    __syncthreads();
    m = fmaxf(fmaxf(red[0],red[1]), fmaxf(red[2],red[3]));
    float e = __expf(v - m);
    float s = e;
    #pragma unroll
    for (int d=32; d>=1; d>>=1) s += __shfl_xor(s, d);
    if ((tid & 63) == 0) red[4 + (tid>>6)] = s;
    __syncthreads();
    s = red[4]+red[5]+red[6]+red[7];
    pc[(size_t)b*65536 + (size_t)c*256 + tid] = e / s;
}

// ======================================================================
// y_c[n][d] = sum_o V[n][o]*pc[o][d]  (V from VT[o][n]) -> bf16 chw flat
// ======================================================================
__global__ __launch_bounds__(256) void yc_kernel(
    const u16* __restrict__ VT, const float* __restrict__ pc, u16* __restrict__ ycb)
{
    __shared__ __align__(16) u16 Vt_l[32*64];
    __shared__ __align__(16) float Pt[32*64];
    const int tid = threadIdx.x;
    const int n0 = blockIdx.x * 64, d0 = blockIdx.y * 64, b = blockIdx.z;
    const int tn = tid >> 4, td = tid & 15;
    float acc[4][4];
    #pragma unroll
    for (int j=0;j<4;j++)
        #pragma unroll
        for (int d=0;d<4;d++) acc[j][d]=0.f;
    for (int ot=0; ot<8; ot++){
        int o0 = ot*32;
        __syncthreads();
        {
            int ol = tid >> 3, cc = tid & 7;
            *(uint4*)&Vt_l[ol*64 + cc*8] = *(const uint4*)(VT + ((size_t)(b*IC + o0 + ol))*NPOS + n0 + cc*8);
            const float* ps = pc + (size_t)b*65536 + (size_t)(o0 + ol)*256 + d0 + cc*8;
            *(float4*)&Pt[ol*64 + cc*8]     = *(const float4*)ps;
            *(float4*)&Pt[ol*64 + cc*8 + 4] = *(const float4*)(ps + 4);
        }
        __syncthreads();
        #pragma unroll 4
        for (int kk=0; kk<32; kk++){
            float4 pv = *(const float4*)&Pt[kk*64 + td*4];
            uint2 vp = *(const uint2*)&Vt_l[kk*64 + tn*4];
            float v0 = blo(vp.x), v1 = bhi(vp.x), v2 = blo(vp.y), v3 = bhi(vp.y);
            acc[0][0] = fmaf(v0, pv.x, acc[0][0]); acc[0][1] = fmaf(v0, pv.y, acc[0][1]);
            acc[0][2] = fmaf(v0, pv.z, acc[0][2]); acc[0][3] = fmaf(v0, pv.w, acc[0][3]);
            acc[1][0] = fmaf(v1, pv.x, acc[1][0]); acc[1][1] = fmaf(v1, pv.y, acc[1][1]);
            acc[1][2] = fmaf(v1, pv.z, acc[1][2]); acc[1][3] = fmaf(v1, pv.w, acc[1][3]);
            acc[2][0] = fmaf(v2, pv.x, acc[2][0]); acc[2][1] = fmaf(v2, pv.y, acc[2][1]);
            acc[2][2] = fmaf(v2, pv.z, acc[2][2]); acc[2][3] = fmaf(v2, pv.w, acc[2][3]);
            acc[3][0] = fmaf(v3, pv.x, acc[3][0]); acc[3][1] = fmaf(v3, pv.y, acc[3][1]);
            acc[3][2] = fmaf(v3, pv.z, acc[3][2]); acc[3][3] = fmaf(v3, pv.w, acc[3][3]);
        }
    }
    #pragma unroll
    for (int j=0;j<4;j++){
        u32 lo = (u32)f2b(acc[j][0]) | ((u32)f2b(acc[j][1]) << 16);
        u32 hi = (u32)f2b(acc[j][2]) | ((u32)f2b(acc[j][3]) << 16);
        *(uint2*)&ycb[((size_t)b*NPOS + n0 + tn*4 + j)*IC + d0 + td*4] = make_uint2(lo,hi);
    }
}

// ======================================================================
// MFMA flash attention, split-K, 16x16x32, wave-private P (r7-proven).
// Bq=64, Bk=64, D=256. LDS exactly 64 KB; 3 barriers/tile; VGPR ~100.
// ======================================================================
__global__ __launch_bounds__(256) void flash_mfma_kernel(
    const u16* __restrict__ Q, const u16* __restrict__ K, const u16* __restrict__ VT,
    u16* __restrict__ opart0, u16* __restrict__ opartx, float* __restrict__ lpart,
    int sshift)
{
    __shared__ __align__(16) u32 Kt[8192];   // 32 KB: K tile (swizzled) + wave-private P/O zones
    __shared__ __align__(16) u32 Vt[8192];   // 32 KB: V^T tile (swizzled)
    const int tid  = threadIdx.x;
    const int w    = tid >> 6;
    const int lane = tid & 63;
    const int q4   = lane >> 4;
    const int l    = lane & 15;
    const int S    = 1 << sshift;
    const int b    = blockIdx.y >> sshift;
    const int seg  = blockIdx.y & (S - 1);
    const int n0   = blockIdx.x * 64;
    const int tiles = 64 >> sshift;
    const int kt0   = seg * tiles;

    // Q fragments (A-layout), held in registers for the whole kernel
    bf16x8 qf[8];
    {
        const u16* qrow = Q + ((size_t)(b*NPOS + n0 + w*16 + l))*IC;
        #pragma unroll
        for (int f=0; f<8; f++)
            qf[f] = *(const bf16x8*)(qrow + f*32 + q4*8);
    }

    f32x4 oacc[16];
    #pragma unroll
    for (int t=0;t<16;t++) oacc[t] = (f32x4){0.f,0.f,0.f,0.f};
    float lrow[4] = {0.f, 0.f, 0.f, 0.f};

    u16* Pz = (u16*)Kt + w*4096;   // wave-private 8KB zone (P matrix / O transpose)

    for (int kti=0; kti<tiles; kti++){
        const int m0 = (kt0 + kti)*64;
        __syncthreads();   // prior S-reads of Kt & PV-reads of Vt/P complete
        // ---- stage K tile: rows m0..m0+63, chunk-swizzled ----
        #pragma unroll
        for (int j=0;j<8;j++){
            int call = w*8 + j;
            int r = call*2 + (lane>>5);
            int c = (lane & 31) ^ (r & 7);
            const u16* g = K + ((size_t)(b*NPOS + m0 + r))*IC + c*8;
            __builtin_amdgcn_global_load_lds(
                (const __attribute__((address_space(1))) u32*)(const void*)g,
                (__attribute__((address_space(3))) u32*)(void*)&Kt[call*256], 16, 0, 0);
        }
        // ---- stage V^T tile: d rows 0..255 x keys m0..m0+63 ----
        #pragma unroll
        for (int j=0;j<8;j++){
            int call = w*8 + j;
            int d = call*8 + (lane>>3);
            int c = (lane & 7) ^ (d & 7);
            const u16* g = VT + ((size_t)(b*IC + d))*NPOS + m0 + c*8;
            __builtin_amdgcn_global_load_lds(
                (const __attribute__((address_space(1))) u32*)(const void*)g,
                (__attribute__((address_space(3))) u32*)(void*)&Vt[call*256], 16, 0, 0);
        }
        __syncthreads();   // staging complete

        // ---- S = Q K^T  (4 key-tiles of 16, 8 k-steps of 32) ----
        f32x4 sac[4];
        #pragma unroll
        for (int t=0;t<4;t++) sac[t] = (f32x4){0.f,0.f,0.f,0.f};
        #pragma unroll
        for (int f=0; f<8; f++){
            #pragma unroll
            for (int t=0;t<4;t++){
                int r = t*16 + l;
                int c = (f*4 + q4) ^ (r & 7);
                bf16x8 kf = *(const bf16x8*)((const u16*)Kt + r*256 + c*8);
                sac[t] = __builtin_amdgcn_mfma_f32_16x16x32_bf16(qf[f], kf, sac[t], 0, 0, 0);
            }
        }
        __syncthreads();   // all Kt reads done before P zones overwrite Kt

        // ---- P = exp(S) (no max: softmax invariant; logits O(10)) ----
        #pragma unroll
        for (int reg=0; reg<4; reg++){
            float p0 = __expf(sac[0][reg]), p1 = __expf(sac[1][reg]);
            float p2 = __expf(sac[2][reg]), p3 = __expf(sac[3][reg]);
            lrow[reg] += (p0+p1) + (p2+p3);
            int m = q4*4 + reg;
            Pz[m*72 + l]      = f2b(p0);
            Pz[m*72 + 16 + l] = f2b(p1);
            Pz[m*72 + 32 + l] = f2b(p2);
            Pz[m*72 + 48 + l] = f2b(p3);
        }

        // ---- O += P V  (16 d-tiles, 2 k-steps of 32) ----
        #pragma unroll
        for (int s=0; s<2; s++){
            bf16x8 pa = *(const bf16x8*)(Pz + l*72 + s*32 + q4*8);
            #pragma unroll
            for (int t=0;t<16;t++){
                int d = t*16 + l;
                int c = (s*4 + q4) ^ (d & 7);
                bf16x8 vb = *(const bf16x8*)((const u16*)Vt + d*64 + c*8);
                oacc[t] = __builtin_amdgcn_mfma_f32_16x16x32_bf16(pa, vb, oacc[t], 0, 0, 0);
            }
        }
    }

    // ---- l reduction across the 16 l-lanes (once, not per tile) ----
    #pragma unroll
    for (int reg=0; reg<4; reg++){
        float v = lrow[reg];
        v += __shfl_xor(v, 1); v += __shfl_xor(v, 2);
        v += __shfl_xor(v, 4); v += __shfl_xor(v, 8);
        if (l == 0)
            lpart[((size_t)(seg*NB + b))*NPOS + n0 + w*16 + q4*4 + reg] = v;
    }

    // ---- epilogue: transpose unnormalized O via wave-private LDS ----
    __syncthreads();
    #pragma unroll
    for (int t=0;t<16;t++)
        #pragma unroll
        for (int reg=0;reg<4;reg++)
            Pz[(t*16 + l)*16 + q4*4 + reg] = f2b(oacc[t][reg]);
    u16* base = (seg == 0) ? opart0 : (opartx + (size_t)(seg-1)*((size_t)NB*IC*NPOS));
    u16* dst = base + (size_t)b*(IC*NPOS) + n0 + w*16;
    for (int p=0; p<32; p++){
        int d = p*8 + (lane>>3);
        u32 val = *(const u32*)(Pz + d*16 + (lane&7)*2);
        *(u32*)(dst + (size_t)d*NPOS + (lane&7)*2) = val;
    }
}

// ======================================================================
// combine: ysT = (sum_s O_s) / (sum_s l_s). In-place on opart0 (=ysT).
// ======================================================================
__global__ __launch_bounds__(256) void combine_kernel(
    u16* __restrict__ opart0, const u16* __restrict__ opartx,
    const float* __restrict__ lpart, int S)
{
    const int idx = blockIdx.x * 256 + threadIdx.x;      // 524288 total
    const int b   = idx >> 17;
    const int rem = idx & 131071;
    const int o   = rem >> 9;
    const int n   = (rem & 511) * 8;
    const size_t base = ((size_t)b*IC + o)*NPOS + n;
    float acc[8] = {0,0,0,0,0,0,0,0};
    float L[8]   = {0,0,0,0,0,0,0,0};
    for (int s=0; s<S; s++){
        const u16* p = (s == 0) ? opart0 : (opartx + (size_t)(s-1)*((size_t)NB*IC*NPOS));
        uint4 v = *(const uint4*)(p + base);
        acc[0] += blo(v.x); acc[1] += bhi(v.x);
        acc[2] += blo(v.y); acc[3] += bhi(v.y);
        acc[4] += blo(v.z); acc[5] += bhi(v.z);
        acc[6] += blo(v.w); acc[7] += bhi(v.w);
        const float* lp = lpart + ((size_t)(s*NB + b))*NPOS + n;
        float4 l0 = *(const float4*)lp;
        float4 l1 = *(const float4*)(lp + 4);
        L[0]+=l0.x; L[1]+=l0.y; L[2]+=l0.z; L[3]+=l0.w;
        L[4]+=l1.x; L[5]+=l1.y; L[6]+=l1.z; L[7]+=l1.w;
    }
    uint4 out;
    out.x = (u32)f2b(acc[0]/L[0]) | ((u32)f2b(acc[1]/L[1]) << 16);
    out.y = (u32)f2b(acc[2]/L[2]) | ((u32)f2b(acc[3]/L[3]) << 16);
    out.z = (u32)f2b(acc[4]/L[4]) | ((u32)f2b(acc[5]/L[5]) << 16);
    out.w = (u32)f2b(acc[6]/L[6]) | ((u32)f2b(acc[7]/L[7]) << 16);
    *(uint4*)(opart0 + base) = out;
}

// ======================================================================
// z = x + gs*(Ws@y_s + Ws_b) + gc*(Wc@y_c + Wc_b)   (fp32 out to d_out)
// ======================================================================
__global__ __launch_bounds__(256) void z_kernel(
    const float* __restrict__ x, const u16* __restrict__ ysT, const u16* __restrict__ ycb,
    const float* __restrict__ wswT, const float* __restrict__ wcwT,
    const float* __restrict__ wsb, const float* __restrict__ wcb,
    const float* __restrict__ gs, const float* __restrict__ gc,
    float* __restrict__ zout)
{
    __shared__ __align__(16) float Wsl[64*32];
    __shared__ __align__(16) float Wcl[64*32];
    const int tid = threadIdx.x;
    const int p = blockIdx.x * 256 + tid;
    const int cbase = blockIdx.y * 32;
    const int b = blockIdx.z;
    {
        int i = tid >> 2, c8 = (tid & 3) * 8;
        const float* s1 = wswT + i*64 + cbase + c8;
        const float* s2 = wcwT + i*64 + cbase + c8;
        *(float4*)&Wsl[i*32 + c8]     = *(const float4*)s1;
        *(float4*)&Wsl[i*32 + c8 + 4] = *(const float4*)(s1+4);
        *(float4*)&Wcl[i*32 + c8]     = *(const float4*)s2;
        *(float4*)&Wcl[i*32 + c8 + 4] = *(const float4*)(s2+4);
    }
    __syncthreads();
    float as[32], ac[32];
    #pragma unroll
    for (int c=0;c<32;c++){ as[c]=0.f; ac[c]=0.f; }
    const u16* ysp = ysT + (size_t)b*(IC*NPOS) + p;
    const u16* ycp = ycb + (size_t)b*(IC*NPOS) + p;
    for (int i=0;i<64;i++){
        float ysv = b2f(ysp[(size_t)i*HW]);
        float ycv = b2f(ycp[(size_t)i*HW]);
        #pragma unroll
        for (int c=0;c<32;c++){
            as[c] = fmaf(Wsl[i*32+c], ysv, as[c]);
            ac[c] = fmaf(Wcl[i*32+c], ycv, ac[c]);
        }
    }
    float gsv = gs[0], gcv = gc[0];
    #pragma unroll
    for (int c=0;c<32;c++){
        int cg = cbase + c;
        float xv = x[((size_t)b*CH + cg)*HW + p];
        float zv = fmaf(gsv, as[c] + wsb[cg], xv);
        zv = fmaf(gcv, ac[c] + wcb[cg], zv);
        zout[((size_t)b*CH + cg)*HW + p] = zv;
    }
}

// ======================================================================
// conv3x3 (64->16) + ReLU. 128 px x 2 o-halves per 256-thr block.
// ======================================================================
__global__ __launch_bounds__(256) void conv1_kernel(
    const float* __restrict__ z, const float* __restrict__ m1wT, const float* __restrict__ m1b,
    float* __restrict__ hmid)
{
    const int tid = threadIdx.x;
    const int p = blockIdx.x * 128 + (tid & 127);
    const int oh = (tid >> 7) * 8;
    const int b = blockIdx.y;
    const int y = p >> 7, xx = p & 127;
    float acc[8];
    #pragma unroll
    for (int o=0;o<8;o++) acc[o]=0.f;
    for (int c=0;c<64;c++){
        const float* zp = z + ((size_t)b*CH + c)*HW;
        #pragma unroll
        for (int t=0;t<9;t++){
            int dy = t/3 - 1, dx = t%3 - 1;
            int yy = y + dy, xv = xx + dx;
            float zv = 0.f;
            if (yy >= 0 && yy < 128 && xv >= 0 && xv < 128) zv = zp[yy*128 + xv];
            const float* w = m1wT + (c*9 + t)*16 + oh;
            #pragma unroll
            for (int o=0;o<8;o++) acc[o] = fmaf(w[o], zv, acc[o]);
        }
    }
    #pragma unroll
    for (int o=0;o<8;o++)
        hmid[((size_t)b*16 + oh + o)*HW + p] = fmaxf(acc[o] + m1b[oh + o], 0.f);
}

// ======================================================================
// conv3x3 (16->1), logit out (fp32)
// ======================================================================
__global__ __launch_bounds__(256) void conv2_kernel(
    const float* __restrict__ hmid, const float* __restrict__ m2w, const float* __restrict__ m2b,
    float* __restrict__ logit)
{
    const int idx = blockIdx.x * 256 + threadIdx.x;
    const int b = idx >> 14, p = idx & 16383;
    const int y = p >> 7, xx = p & 127;
    float acc = 0.f;
    for (int c=0;c<16;c++){
        const float* hp = hmid + ((size_t)b*16 + c)*HW;
        #pragma unroll
        for (int t=0;t<9;t++){
            int dy = t/3 - 1, dx = t%3 - 1;
            int yy = y + dy, xv = xx + dx;
            if (yy >= 0 && yy < 128 && xv >= 0 && xv < 128)
                acc = fmaf(m2w[c*9+t], hp[yy*128 + xv], acc);
        }
    }
    logit[idx] = acc + m2b[0];
}

// ======================================================================
extern "C" void kernel_launch(void* const* d_in, const int* in_sizes, int n_in,
                              void* d_out, int out_size, void* d_ws, size_t ws_size,
                              hipStream_t stream)
{
    const float* x    = (const float*)d_in[0];
    const float* g_w  = (const float*)d_in[1];
    const float* g_b  = (const float*)d_in[2];
    const float* th_w = (const float*)d_in[3];
    const float* th_b = (const float*)d_in[4];
    const float* ph_w = (const float*)d_in[5];
    const float* ph_b = (const float*)d_in[6];
    const float* ws_w = (const float*)d_in[7];
    const float* ws_b = (const float*)d_in[8];
    const float* wc_w = (const float*)d_in[9];
    const float* wc_b = (const float*)d_in[10];
    const float* gs   = (const float*)d_in[11];
    const float* gc   = (const float*)d_in[12];
    const float* m1w  = (const float*)d_in[13];
    const float* m1b  = (const float*)d_in[14];
    const float* m2w  = (const float*)d_in[15];
    const float* m2b  = (const float*)d_in[16];

    char* ws = (char*)d_ws;
    u16*   Qb   = (u16*)  (ws + 0);
    u16*   Kb   = (u16*)  (ws + 8388608);
    u16*   VTb  = (u16*)  (ws + 16777216);
    u16*   ysT  = (u16*)  (ws + 25165824);
    u16*   ycb  = (u16*)  (ws + 33554432);
    u16*   wbf  = (u16*)  (ws + 41943040);
    float* pc   = (float*)(ws + 42991616);
    float* fcp  = (float*)(ws + 44040192);   // 4MB n-partials (dead hmid region)
    float* hmid = (float*)(ws + 44040192);
    float* lpart= (float*)(ws + 44040192);   // used during flash window only
    float* wswT = (float*)(ws + 48234496);
    float* wcwT = (float*)(ws + 48250880);
    float* m1wT = (float*)(ws + 48267264);
    u16*   opartx = (u16*)(ws + 48304128);   // (S-1) x 8MB segments

    float* logit = (float*)d_out;
    float* zout  = (float*)d_out + 65536;

    // choose split-K factor by available workspace (constant per session)
    int sshift = 0;
    if (ws_size >= 48304128ULL + 3ULL*8388608ULL)      sshift = 2;
    else if (ws_size >= 48304128ULL + 1ULL*8388608ULL) sshift = 1;

    prep_kernel<<<256, 256, 0, stream>>>(ws_w, wc_w, m1w, th_w, ph_w, g_w,
                                         wswT, wcwT, m1wT, wbf);
    qkv_mfma_kernel<<<dim3(64,4,3), 256, 0, stream>>>(x, wbf, th_b, ph_b, g_b, Qb, Kb, VTb);
    fc_mfma_kernel<<<dim3(4,4,16), 256, 0, stream>>>(Qb, Kb, fcp);
    softmax_fc_kernel<<<1024, 256, 0, stream>>>(fcp, pc);
    yc_kernel<<<dim3(64,4,4), 256, 0, stream>>>(VTb, pc, ycb);
    flash_mfma_kernel<<<dim3(64, NB << sshift), 256, 0, stream>>>(Qb, Kb, VTb, ysT, opartx, lpart, sshift);
    combine_kernel<<<2048, 256, 0, stream>>>(ysT, opartx, lpart, 1 << sshift);
    z_kernel<<<dim3(64,2,4), 256, 0, stream>>>(x, ysT, ycb, wswT, wcwT, ws_b, wc_b, gs, gc, zout);
    conv1_kernel<<<dim3(128,4), 256, 0, stream>>>(zout, m1wT, m1b, hmid);
    conv2_kernel<<<256, 256, 0, stream>>>(hmid, m2w, m2b, logit);
}